// Round 8
// baseline (87.980 us; speedup 1.0000x reference)
//
#include <hip/hip_runtime.h>
#include <stdint.h>

// CorrelationLayer via MFMA Gram tiles, vectorized LDS staging, 2 rows/block.
// out[j*7+i, h, w] = sum_c x[c,h,w] * y[c,h+j-3,w+i-3], zero-padded.
//
// R8: block = (2 h-rows, 64-px slab), 512 thr = 8 waves, wave-unit =
// (h0+dh, 16-px tile ww). LDS y tile: rows h0-3..h0+4 (8) x cols ws_blk-4..
// +71 (76) x k-chunk 32 (padded 40) bf16, k-contiguous per col.
// Staging item = (row, k-quad, col4): 4x float4 global loads (4 w x 4 k) ->
// 8 pkbf -> 4x ds_write_b64; k-dword XOR swizzle (kp ^ ((col>>2 & 3)<<2))
// breaks the 80B-stride bank cycle; b128 reads invert it via g ^ ((col>>2)&3).
// Interior blocks run a SAFE staging path (no validity logic).
// Verified math carried from R6/R7: A/B lane {m|n}=l&15, k=(l>>4)*8+e;
// C/D col=lane&15, row=(lane>>4)*4+reg; extraction slab 16x34, i=g / g+4.
// Grid 192 h-pairs x 8 slabs = 1536; XCD k owns h-pairs [24k, 24k+24).

typedef __attribute__((ext_vector_type(8))) short short8;
typedef __attribute__((ext_vector_type(4))) float floatx4;

constexpr int C = 128;
constexpr int H = 384;
constexpr int W = 512;
constexpr int HW = H * W;

constexpr int NROW = 8;
constexpr int NCOL = 76;             // LDS col 0 = abs ws_blk - 4
constexpr int KPD  = 20;             // dwords per col (40 bf16, k padded 32->40)
constexpr int ROWB = NCOL * KPD * 4; // 6080 B per row

__device__ __forceinline__ uint32_t pkbf(float a, float b) {
  uint32_t ua = (__float_as_uint(a) + 0x8000u) >> 16;
  uint32_t ub = (__float_as_uint(b) + 0x8000u) & 0xffff0000u;
  return ua | ub;
}

union S8U { uint32_t u[4]; short8 s; };

template <bool SAFE>
__device__ __forceinline__ void stage_chunk(const float* __restrict__ y,
                                            uint32_t* __restrict__ lds32,
                                            int kc, int h0, int ws_blk,
                                            int tid) {
  // items: 8 rows x 8 k-quads x 19 col4 = 1216
#pragma unroll
  for (int it = 0; it < 3; ++it) {
    const int u = it * 512 + tid;
    if (u < 1216) {
      const int c4  = u % 19;
      const int t1  = u / 19;        // 0..63
      const int kq  = t1 & 7;
      const int row = t1 >> 3;
      const int r_abs = h0 - 3 + row;
      const int cb    = ws_blk - 4 + 4 * c4;
      bool val = true;
      int r = r_abs, cc = cb;
      if (!SAFE) {
        val = (r_abs >= 0) & (r_abs < H) & (cb >= 0) & (cb <= W - 4);
        r   = r_abs < 0 ? 0 : (r_abs >= H ? H - 1 : r_abs);
        cc  = cb < 0 ? 0 : (cb > W - 4 ? W - 4 : cb);
      }
      const float* src = y + (size_t)(kc * 32 + kq * 4) * HW +
                         (size_t)r * W + cc;
      const float4 p0 = *reinterpret_cast<const float4*>(src);
      const float4 p1 = *reinterpret_cast<const float4*>(src + HW);
      const float4 p2 = *reinterpret_cast<const float4*>(src + 2 * HW);
      const float4 p3 = *reinterpret_cast<const float4*>(src + 3 * HW);
      const int swz   = (c4 & 3) << 2;
      const int dbase = (row * NCOL + 4 * c4) * KPD + ((2 * kq) ^ swz);
      uint32_t lo, hi;
      lo = pkbf(p0.x, p1.x); hi = pkbf(p2.x, p3.x);
      if (!SAFE) { lo = val ? lo : 0u; hi = val ? hi : 0u; }
      *reinterpret_cast<uint2*>(&lds32[dbase]) = make_uint2(lo, hi);
      lo = pkbf(p0.y, p1.y); hi = pkbf(p2.y, p3.y);
      if (!SAFE) { lo = val ? lo : 0u; hi = val ? hi : 0u; }
      *reinterpret_cast<uint2*>(&lds32[dbase + KPD]) = make_uint2(lo, hi);
      lo = pkbf(p0.z, p1.z); hi = pkbf(p2.z, p3.z);
      if (!SAFE) { lo = val ? lo : 0u; hi = val ? hi : 0u; }
      *reinterpret_cast<uint2*>(&lds32[dbase + 2 * KPD]) = make_uint2(lo, hi);
      lo = pkbf(p0.w, p1.w); hi = pkbf(p2.w, p3.w);
      if (!SAFE) { lo = val ? lo : 0u; hi = val ? hi : 0u; }
      *reinterpret_cast<uint2*>(&lds32[dbase + 3 * KPD]) = make_uint2(lo, hi);
    }
  }
}

__global__ __launch_bounds__(512, 4)
void corr_mfma(const float* __restrict__ x, const float* __restrict__ y,
               float* __restrict__ out) {
  __shared__ uint32_t lds32[NROW * NCOL * KPD];   // 48640 B

  const int bid  = blockIdx.x;
  const int idx  = bid >> 3;                   // 0..191
  const int hp   = (bid & 7) * 24 + (idx >> 3);
  const int slab = idx & 7;
  const int h0     = hp * 2;
  const int ws_blk = slab * 64;
  const int tid  = threadIdx.x;
  const int wv   = tid >> 6;
  const int lane = tid & 63;
  const int m  = lane & 15;
  const int g  = lane >> 4;
  const int dh = wv >> 2;        // 0..1
  const int ww = wv & 3;         // 0..3
  const int h  = h0 + dh;
  const int ws = ws_blk + ww * 16;

  const bool safe = (h0 >= 4) & (h0 <= H - 6) & (slab >= 1) & (slab <= 6);

  floatx4 acc[7][2];
#pragma unroll
  for (int j = 0; j < 7; ++j) {
    acc[j][0] = (floatx4){0.f, 0.f, 0.f, 0.f};
    acc[j][1] = (floatx4){0.f, 0.f, 0.f, 0.f};
  }

  // ---- A fragments preload: af[kc], A[m][k] = x[k][h][ws+m], k=g*8+e ----
  short8 af[4];
  {
    const float* xb = x + (size_t)(g * 8) * HW + (size_t)h * W + (ws + m);
#pragma unroll
    for (int kc = 0; kc < 4; ++kc) {
      float f[8];
#pragma unroll
      for (int e = 0; e < 8; ++e) f[e] = xb[(size_t)(kc * 32 + e) * HW];
      S8U s;
      s.u[0] = pkbf(f[0], f[1]);
      s.u[1] = pkbf(f[2], f[3]);
      s.u[2] = pkbf(f[4], f[5]);
      s.u[3] = pkbf(f[6], f[7]);
      af[kc] = s.s;
    }
  }

  // per-lane b128 read offsets (byte, within a row slab), swizzle-inverted
  const int col0 = 1 + ww * 16 + m;            // tile0 LDS col
  int col1 = col0 + 16;                        // tile1 (clamped; unused lanes)
  if (col1 > NCOL - 1) col1 = NCOL - 1;
  const int fb0 = col0 * (KPD * 4) + (g ^ ((col0 >> 2) & 3)) * 16;
  const int fb1 = col1 * (KPD * 4) + (g ^ ((col1 >> 2) & 3)) * 16;

  for (int kc = 0; kc < 4; ++kc) {
    if (kc) __syncthreads();                   // protect previous chunk reads
    if (safe) stage_chunk<true >(y, lds32, kc, h0, ws_blk, tid);
    else      stage_chunk<false>(y, lds32, kc, h0, ws_blk, tid);
    __syncthreads();

#pragma unroll
    for (int j = 0; j < 7; ++j) {
      const uint8_t* rb =
          reinterpret_cast<const uint8_t*>(lds32) + (dh + j) * ROWB;
      const short8 b0 = *reinterpret_cast<const short8*>(rb + fb0);
      const short8 b1 = *reinterpret_cast<const short8*>(rb + fb1);
      acc[j][0] = __builtin_amdgcn_mfma_f32_16x16x32_bf16(af[kc], b0, acc[j][0], 0, 0, 0);
      acc[j][1] = __builtin_amdgcn_mfma_f32_16x16x32_bf16(af[kc], b1, acc[j][1], 0, 0, 0);
    }
  }

  // ---- extraction: per-wave 16x34 f32 slab (reuses lds32 after barrier) ----
  __syncthreads();
  float* slabp = reinterpret_cast<float*>(lds32) + wv * 544;
#pragma unroll
  for (int j = 0; j < 7; ++j) {
#pragma unroll
    for (int q = 0; q < 4; ++q) {
      slabp[(g * 4 + q) * 34 + m]      = acc[j][0][q];   // cols 0..15
      slabp[(g * 4 + q) * 34 + 16 + m] = acc[j][1][q];   // cols 16..31
    }
    const float vo0 = slabp[m * 34 + m + g];             // i = g
    const float vo1 = slabp[m * 34 + m + g + 4];         // i = g+4 (g<3)
    float* ob = out + (size_t)(j * 7 + g) * HW + (size_t)h * W + (ws + m);
    *ob = vo0;
    if (g < 3) ob[(size_t)4 * HW] = vo1;
  }
}

extern "C" void kernel_launch(void* const* d_in, const int* in_sizes, int n_in,
                              void* d_out, int out_size, void* d_ws, size_t ws_size,
                              hipStream_t stream) {
  const float* x = (const float*)d_in[0];
  const float* y = (const float*)d_in[1];
  float* out = (float*)d_out;
  corr_mfma<<<dim3(192 * 8), dim3(512), 0, stream>>>(x, y, out);
}